// Round 7
// baseline (183.679 us; speedup 1.0000x reference)
//
#include <hip/hip_runtime.h>
#include <math.h>

// Problem constants (fixed by the reference file)
#define B_    4
#define LQ_   4096
#define C_    384
#define NH_   6
#define NP_   4
#define HL_   64
#define WL_   64
#define LV_   (HL_ * WL_)          // 4096
#define ROWS_ (B_ * LQ_)           // 16384
#define EPS_  1e-6f
#define NOFF_ 48                   // NH*NL*NP*2
#define NLOG_ 24                   // NH*NL*NP

typedef unsigned short u16;
typedef unsigned int   u32;
typedef __bf16 bf16x8 __attribute__((ext_vector_type(8)));
typedef float  f32x4  __attribute__((ext_vector_type(4)));

__device__ __forceinline__ u16 f2bf(float f) {
    u32 u = __float_as_uint(f);
    u += 0x7fff + ((u >> 16) & 1);          // RTNE
    return (u16)(u >> 16);
}
__device__ __forceinline__ u32 pack2bf(float a, float b) {
    return (u32)f2bf(a) | ((u32)f2bf(b) << 16);
}

__device__ __forceinline__ f32x4 mfma16(bf16x8 a, bf16x8 b, f32x4 c) {
    return __builtin_amdgcn_mfma_f32_16x16x32_bf16(a, b, c, 0, 0, 0);
}

// async global->LDS, 16 bytes per lane; LDS dst must be wave-uniform base + lane*16
__device__ __forceinline__ void gl_lds16(const u16* g, u16* l) {
    __builtin_amdgcn_global_load_lds(
        (const __attribute__((address_space(1))) unsigned int*)g,
        (__attribute__((address_space(3))) unsigned int*)l, 16, 0, 0);
}

// ---------------------------------------------------------------------------
// Fused LayerNorm (blocks 0..8191, vectorized) + weight prep (rest).
// ---------------------------------------------------------------------------
#define LN_BLOCKS_   8192
#define PREP_BLOCKS_ 1273

__global__ __launch_bounds__(256) void ln_prep(
    const float* __restrict__ query, const float* __restrict__ feat,
    const float* __restrict__ qg, const float* __restrict__ qbv,
    const float* __restrict__ fg, const float* __restrict__ fbv,
    u16* __restrict__ qout, u16* __restrict__ fout,
    const float* __restrict__ Wv, const float* __restrict__ Wout,
    const float* __restrict__ Wo, const float* __restrict__ Wa,
    const float* __restrict__ bo, const float* __restrict__ ba,
    u16* __restrict__ WvT, u16* __restrict__ WoutT, u16* __restrict__ WcT,
    float* __restrict__ bias_c)
{
    if (blockIdx.x < LN_BLOCKS_) {
        int wid  = threadIdx.x >> 6;
        int lane = threadIdx.x & 63;
        int row  = blockIdx.x * 4 + wid;          // 0 .. 32767
        const float *src, *g, *bsh;
        u16* dst;
        int r;
        if (row < ROWS_) { src = query; g = qg; bsh = qbv; dst = qout; r = row; }
        else             { src = feat;  g = fg; bsh = fbv; dst = fout; r = row - ROWS_; }

        const float* x = src + (size_t)r * C_;
        float4 a4 = *(const float4*)(x + 4 * lane);
        float2 a2 = *(const float2*)(x + 256 + 2 * lane);
        float v0 = a4.x, v1 = a4.y, v2 = a4.z, v3 = a4.w, v4 = a2.x, v5 = a2.y;

        float s = v0 + v1 + v2 + v3 + v4 + v5;
#pragma unroll
        for (int off = 32; off; off >>= 1) s += __shfl_xor(s, off);
        float mu = s * (1.f / C_);

        float d0 = v0 - mu, d1 = v1 - mu, d2 = v2 - mu;
        float d3 = v3 - mu, d4 = v4 - mu, d5 = v5 - mu;
        float s2 = d0*d0 + d1*d1 + d2*d2 + d3*d3 + d4*d4 + d5*d5;
#pragma unroll
        for (int off = 32; off; off >>= 1) s2 += __shfl_xor(s2, off);
        float rs = rsqrtf(s2 * (1.f / C_) + EPS_);

        float4 g4 = *(const float4*)(g + 4 * lane);
        float4 b4 = *(const float4*)(bsh + 4 * lane);
        float2 g2 = *(const float2*)(g + 256 + 2 * lane);
        float2 b2 = *(const float2*)(bsh + 256 + 2 * lane);

        float o0 = d0 * rs * g4.x + b4.x;
        float o1 = d1 * rs * g4.y + b4.y;
        float o2 = d2 * rs * g4.z + b4.z;
        float o3 = d3 * rs * g4.w + b4.w;
        float o4 = d4 * rs * g2.x + b2.x;
        float o5 = d5 * rs * g2.y + b2.y;

        u16* y = dst + (size_t)r * C_;
        uint2 w0; w0.x = pack2bf(o0, o1); w0.y = pack2bf(o2, o3);
        *(uint2*)(y + 4 * lane) = w0;
        *(u32*)(y + 256 + 2 * lane) = pack2bf(o4, o5);
    } else {
        const int KN = 384 * 384;
        int idx = (blockIdx.x - LN_BLOCKS_) * 256 + threadIdx.x;
        if (idx < KN) {
            int n = idx / 384, k = idx - n * 384;
            WvT[idx] = f2bf(Wv[k * 384 + n]);
        } else if (idx < 2 * KN) {
            int t = idx - KN;
            int n = t / 384, k = t - n * 384;
            WoutT[t] = f2bf(Wout[k * 384 + n]);
        } else if (idx < 2 * KN + 80 * 384) {
            int t = idx - 2 * KN;
            int n = t / 384, k = t - n * 384;
            float v = (n < 48) ? Wo[k * 48 + n] : (n < 72 ? Wa[k * 24 + (n - 48)] : 0.f);
            WcT[t] = f2bf(v);
        } else if (idx < 2 * KN + 80 * 384 + 80) {
            int n = idx - (2 * KN + 80 * 384);
            bias_c[n] = (n < 48) ? bo[n] : (n < 72 ? ba[n - 48] : 0.f);
        }
    }
}

// ---------------------------------------------------------------------------
// Combined MFMA GEMM dispatch, 512 blocks x 256 threads, BK=64 (two 32-col
// slices staged per barrier -> 6 drains instead of 12):
//   blocks 0..383:  value path, 128x128 tile: valb = fb @ WvT^T + bv (bf16)
//   blocks 384..511: small path, 128x80 tile: [offs|logits] = qb @ WcT^T + bias_c
// LDS: As 2x(128x32) + Bs 2x(128x32) = 32 KB.
// ---------------------------------------------------------------------------
__global__ __launch_bounds__(256) void gemm_combined(
    const u16* __restrict__ fb, const u16* __restrict__ qb,
    const u16* __restrict__ WvT, const u16* __restrict__ WcT,
    const float* __restrict__ bv, const float* __restrict__ bias_c,
    u16* __restrict__ valb, float* __restrict__ offs, float* __restrict__ logits)
{
    const int K = 384;
    __shared__ __align__(16) u16 As[2][128 * 32];
    __shared__ __align__(16) u16 Bs[2][128 * 32];

    int g    = blockIdx.x;
    int tid  = threadIdx.x;
    int lane = tid & 63, wid = tid >> 6;
    int fr = lane & 15, quad = lane >> 4;

    int srow = tid >> 2;                  // 0..63
    int scol = (tid & 3) * 8;             // element col within a 32-slice

    if (g < 384) {
        // ---------------- value path: 128x128 ----------------
        int m0 = (g / 3) * 128, n0 = (g % 3) * 128;
        const u16* agp0 = fb  + (size_t)(m0 + srow) * K + scol;
        const u16* agp1 = fb  + (size_t)(m0 + 64 + srow) * K + scol;
        const u16* bgp0 = WvT + (size_t)(n0 + srow) * K + scol;
        const u16* bgp1 = WvT + (size_t)(n0 + 64 + srow) * K + scol;

        int wm = (wid >> 1) * 64, wn = (wid & 1) * 64;

        f32x4 zero = {0.f, 0.f, 0.f, 0.f};
        f32x4 acc[4][4];
#pragma unroll
        for (int i = 0; i < 4; ++i)
#pragma unroll
            for (int j = 0; j < 4; ++j) acc[i][j] = zero;

        for (int k0 = 0; k0 < K; k0 += 64) {
#pragma unroll
            for (int s = 0; s < 2; ++s) {
                int kk = k0 + s * 32;
                gl_lds16(agp0 + kk, As[s] + tid * 8);
                gl_lds16(agp1 + kk, As[s] + 2048 + tid * 8);
                gl_lds16(bgp0 + kk, Bs[s] + tid * 8);
                gl_lds16(bgp1 + kk, Bs[s] + 2048 + tid * 8);
            }
            __syncthreads();
#pragma unroll
            for (int s = 0; s < 2; ++s) {
                bf16x8 af[4], bfr[4];
#pragma unroll
                for (int i = 0; i < 4; ++i)
                    af[i] = *(bf16x8*)&As[s][(wm + i * 16 + fr) * 32 + quad * 8];
#pragma unroll
                for (int j = 0; j < 4; ++j)
                    bfr[j] = *(bf16x8*)&Bs[s][(wn + j * 16 + fr) * 32 + quad * 8];
#pragma unroll
                for (int i = 0; i < 4; ++i)
#pragma unroll
                    for (int j = 0; j < 4; ++j)
                        acc[i][j] = mfma16(af[i], bfr[j], acc[i][j]);
            }
            __syncthreads();
        }

#pragma unroll
        for (int i = 0; i < 4; ++i) {
            int row = m0 + wm + i * 16 + quad * 4;
#pragma unroll
            for (int j = 0; j < 4; ++j) {
                int col = n0 + wn + j * 16 + fr;
                float bcol = bv[col];
#pragma unroll
                for (int r = 0; r < 4; ++r)
                    valb[(size_t)(row + r) * C_ + col] = f2bf(acc[i][j][r] + bcol);
            }
        }
    } else {
        // ---------------- small path: 128x80 ----------------
        int m0 = (g - 384) * 128;
        const u16* agp0 = qb + (size_t)(m0 + srow) * K + scol;
        const u16* agp1 = qb + (size_t)(m0 + 64 + srow) * K + scol;
        const u16* bgp0 = WcT + (size_t)srow * K + scol;           // rows 0..63
        const u16* bgp1 = WcT + (size_t)(64 + srow) * K + scol;    // rows 64..79 (tid<64)

        int wm = wid * 32;

        f32x4 zero = {0.f, 0.f, 0.f, 0.f};
        f32x4 acc[2][5];
#pragma unroll
        for (int i = 0; i < 2; ++i)
#pragma unroll
            for (int j = 0; j < 5; ++j) acc[i][j] = zero;

        for (int k0 = 0; k0 < K; k0 += 64) {
#pragma unroll
            for (int s = 0; s < 2; ++s) {
                int kk = k0 + s * 32;
                gl_lds16(agp0 + kk, As[s] + tid * 8);
                gl_lds16(agp1 + kk, As[s] + 2048 + tid * 8);
                gl_lds16(bgp0 + kk, Bs[s] + tid * 8);
                if (tid < 64) gl_lds16(bgp1 + kk, Bs[s] + 2048 + tid * 8);
            }
            __syncthreads();
#pragma unroll
            for (int s = 0; s < 2; ++s) {
                bf16x8 af[2], bfr[5];
#pragma unroll
                for (int i = 0; i < 2; ++i)
                    af[i] = *(bf16x8*)&As[s][(wm + i * 16 + fr) * 32 + quad * 8];
#pragma unroll
                for (int j = 0; j < 5; ++j)
                    bfr[j] = *(bf16x8*)&Bs[s][(j * 16 + fr) * 32 + quad * 8];
#pragma unroll
                for (int i = 0; i < 2; ++i)
#pragma unroll
                    for (int j = 0; j < 5; ++j)
                        acc[i][j] = mfma16(af[i], bfr[j], acc[i][j]);
            }
            __syncthreads();
        }

#pragma unroll
        for (int i = 0; i < 2; ++i) {
            int row = m0 + wm + i * 16 + quad * 4;
#pragma unroll
            for (int j = 0; j < 5; ++j) {
                int col = j * 16 + fr;
                if (col < 72) {
                    float bcol = bias_c[col];
#pragma unroll
                    for (int r = 0; r < 4; ++r) {
                        float v = acc[i][j][r] + bcol;
                        if (col < 48) offs[(size_t)(row + r) * NOFF_ + col] = v;
                        else          logits[(size_t)(row + r) * NLOG_ + (col - 48)] = v;
                    }
                }
            }
        }
    }
}

// ---------------------------------------------------------------------------
// Standalone sampler: NO LDS, NO barriers. One thread = one (q, d-chunk):
// softmax+coords in registers, 16 bf16x8 gathers, one 16B coalesced store.
// 384 threads = 8 queries/block; 2048 blocks; XCD swizzle keeps one batch's
// value (3.1 MB) per XCD-pair L2.
// ---------------------------------------------------------------------------
__global__ __launch_bounds__(384) void sampler(
    const u16*  __restrict__ value,    // [B*LV, 384] bf16
    const float* __restrict__ rp,      // [B*LQ, 2]
    const float* __restrict__ offs,    // [B*LQ, 48]
    const float* __restrict__ logits,  // [B*LQ, 24]
    u16* __restrict__ attn)            // [B*LQ, 384] bf16
{
    int t = threadIdx.x;
    int g = blockIdx.x;
    int b     = (g & 7) >> 1;                        // batch -> XCD pair
    int local = ((g >> 3) << 1) | (g & 1);           // 0..511 within batch
    int q  = t / 48, dc = t - q * 48;
    int h  = dc >> 3;
    int col0 = dc << 3;                              // 0,8,...,376
    int r  = b * LQ_ + local * 8 + q;

    float4 lg  = *(const float4*)(logits + (size_t)r * NLOG_ + h * 4);
    float2 rpv = *(const float2*)(rp + (size_t)r * 2);
    float4 of0 = *(const float4*)(offs + (size_t)r * NOFF_ + h * 8);
    float4 of1 = *(const float4*)(offs + (size_t)r * NOFF_ + h * 8 + 4);

    float mx = fmaxf(fmaxf(lg.x, lg.y), fmaxf(lg.z, lg.w));
    float e0 = __expf(lg.x - mx), e1 = __expf(lg.y - mx);
    float e2 = __expf(lg.z - mx), e3 = __expf(lg.w - mx);
    float rden = 1.f / (e0 + e1 + e2 + e3);
    float aws[4] = {e0 * rden, e1 * rden, e2 * rden, e3 * rden};
    float oxs[4] = {of0.x, of0.z, of1.x, of1.z};
    float oys[4] = {of0.y, of0.w, of1.y, of1.w};

    const u16* vbase = value + (size_t)b * LV_ * C_ + col0;
    float acc[8] = {0.f, 0.f, 0.f, 0.f, 0.f, 0.f, 0.f, 0.f};
#pragma unroll
    for (int p = 0; p < NP_; ++p) {
        float x = rpv.x * (float)WL_ + oxs[p] - 0.5f;
        float y = rpv.y * (float)HL_ + oys[p] - 0.5f;
        float x0f = floorf(x), y0f = floorf(y);
        float wx = x - x0f, wy = y - y0f;
        int x0 = (int)x0f, y0 = (int)y0f;
#pragma unroll
        for (int c = 0; c < 4; ++c) {
            int xi = x0 + (c & 1);
            int yi = y0 + (c >> 1);
            bool valid = (xi >= 0) && (xi < WL_) && (yi >= 0) && (yi < HL_);
            int xc = xi < 0 ? 0 : (xi > WL_ - 1 ? WL_ - 1 : xi);
            int yc = yi < 0 ? 0 : (yi > HL_ - 1 ? HL_ - 1 : yi);
            float w = ((c & 1) ? wx : 1.f - wx) * ((c >> 1) ? wy : 1.f - wy) * aws[p];
            w = valid ? w : 0.f;
            bf16x8 vv = *(const bf16x8*)(vbase + (size_t)(yc * WL_ + xc) * C_);
#pragma unroll
            for (int e = 0; e < 8; ++e) acc[e] += w * (float)vv[e];
        }
    }

    uint4 o;
    o.x = pack2bf(acc[0], acc[1]);
    o.y = pack2bf(acc[2], acc[3]);
    o.z = pack2bf(acc[4], acc[5]);
    o.w = pack2bf(acc[6], acc[7]);
    *(uint4*)(attn + (size_t)r * C_ + col0) = o;
}

// ---------------------------------------------------------------------------
// Out GEMM: out = query + gamma * (attn @ WoutT^T + bout). 128x128 tile,
// BK=64 staging (6 drains). 384 blocks x 256 threads.
// ---------------------------------------------------------------------------
__global__ __launch_bounds__(256) void out_gemm(
    const u16* __restrict__ A, const u16* __restrict__ Bt,
    const float* __restrict__ bout, const float* __restrict__ gamma,
    const float* __restrict__ query, float* __restrict__ out)
{
    const int K = 384;
    __shared__ __align__(16) u16 As[2][128 * 32];
    __shared__ __align__(16) u16 Bs[2][128 * 32];

    int g    = blockIdx.x;
    int tid  = threadIdx.x;
    int lane = tid & 63, wid = tid >> 6;
    int fr = lane & 15, quad = lane >> 4;

    int srow = tid >> 2;
    int scol = (tid & 3) * 8;

    int m0 = (g / 3) * 128, n0 = (g % 3) * 128;
    const u16* agp0 = A  + (size_t)(m0 + srow) * K + scol;
    const u16* agp1 = A  + (size_t)(m0 + 64 + srow) * K + scol;
    const u16* bgp0 = Bt + (size_t)(n0 + srow) * K + scol;
    const u16* bgp1 = Bt + (size_t)(n0 + 64 + srow) * K + scol;

    int wm = (wid >> 1) * 64, wn = (wid & 1) * 64;

    f32x4 zero = {0.f, 0.f, 0.f, 0.f};
    f32x4 acc[4][4];
#pragma unroll
    for (int i = 0; i < 4; ++i)
#pragma unroll
        for (int j = 0; j < 4; ++j) acc[i][j] = zero;

    for (int k0 = 0; k0 < K; k0 += 64) {
#pragma unroll
        for (int s = 0; s < 2; ++s) {
            int kk = k0 + s * 32;
            gl_lds16(agp0 + kk, As[s] + tid * 8);
            gl_lds16(agp1 + kk, As[s] + 2048 + tid * 8);
            gl_lds16(bgp0 + kk, Bs[s] + tid * 8);
            gl_lds16(bgp1 + kk, Bs[s] + 2048 + tid * 8);
        }
        __syncthreads();
#pragma unroll
        for (int s = 0; s < 2; ++s) {
            bf16x8 af[4], bfr[4];
#pragma unroll
            for (int i = 0; i < 4; ++i)
                af[i] = *(bf16x8*)&As[s][(wm + i * 16 + fr) * 32 + quad * 8];
#pragma unroll
            for (int j = 0; j < 4; ++j)
                bfr[j] = *(bf16x8*)&Bs[s][(wn + j * 16 + fr) * 32 + quad * 8];
#pragma unroll
            for (int i = 0; i < 4; ++i)
#pragma unroll
                for (int j = 0; j < 4; ++j)
                    acc[i][j] = mfma16(af[i], bfr[j], acc[i][j]);
        }
        __syncthreads();
    }

#pragma unroll
    for (int i = 0; i < 4; ++i) {
        int row = m0 + wm + i * 16 + quad * 4;
#pragma unroll
        for (int j = 0; j < 4; ++j) {
            int col = n0 + wn + j * 16 + fr;
            float bc = bout[col], gm = gamma[col];
#pragma unroll
            for (int r = 0; r < 4; ++r) {
                size_t o = (size_t)(row + r) * C_ + col;
                out[o] = query[o] + gm * (acc[i][j][r] + bc);
            }
        }
    }
}

// ---------------------------------------------------------------------------
extern "C" void kernel_launch(void* const* d_in, const int* in_sizes, int n_in,
                              void* d_out, int out_size, void* d_ws, size_t ws_size,
                              hipStream_t stream)
{
    const float* query  = (const float*)d_in[0];
    const float* rp     = (const float*)d_in[1];
    const float* feat   = (const float*)d_in[2];
    const float* gamma  = (const float*)d_in[9];
    const float* Wv     = (const float*)d_in[10];
    const float* bv     = (const float*)d_in[11];
    const float* Wo     = (const float*)d_in[12];
    const float* bo     = (const float*)d_in[13];
    const float* Wa     = (const float*)d_in[14];
    const float* ba     = (const float*)d_in[15];
    const float* Wout   = (const float*)d_in[16];
    const float* bout   = (const float*)d_in[17];
    float* out = (float*)d_out;

    // Workspace layout
    u16* wsu    = (u16*)d_ws;
    u16* qb     = wsu;                                   // 16384*384
    u16* fb     = qb    + (size_t)ROWS_ * C_;
    u16* valb   = fb    + (size_t)ROWS_ * C_;
    u16* attnb  = valb  + (size_t)ROWS_ * C_;
    u16* WvT    = attnb + (size_t)ROWS_ * C_;            // 384*384
    u16* WoutT  = WvT   + 384 * 384;
    u16* WcT    = WoutT + 384 * 384;                     // 80*384
    float* offs   = (float*)(WcT + 80 * 384);            // 16384*48
    float* logits = offs + (size_t)ROWS_ * NOFF_;        // 16384*24
    float* bias_c = logits + (size_t)ROWS_ * NLOG_;      // 80

    // 1) LayerNorm (q,f -> bf16, vectorized) + weight transpose/convert
    ln_prep<<<LN_BLOCKS_ + PREP_BLOCKS_, 256, 0, stream>>>(
        query, feat,
        (const float*)d_in[5], (const float*)d_in[6],
        (const float*)d_in[7], (const float*)d_in[8],
        qb, fb, Wv, Wout, Wo, Wa, bo, ba, WvT, WoutT, WcT, bias_c);

    // 2) value GEMM 128x128 (384 blocks) + offs/logits GEMM (128 blocks), BK=64
    gemm_combined<<<512, 256, 0, stream>>>(fb, qb, WvT, WcT, bv, bias_c,
                                           valb, offs, logits);

    // 3) sampler: barrier-free, register-only, coalesced bf16 attn out
    sampler<<<2048, 384, 0, stream>>>(valb, rp, offs, logits, attnb);

    // 4) out = query + gamma * (attn @ Wout + bout), BK=64
    out_gemm<<<384, 256, 0, stream>>>(attnb, WoutT, bout, gamma, query, out);
}

// Round 8
// 168.827 us; speedup vs baseline: 1.0880x; 1.0880x over previous
//
#include <hip/hip_runtime.h>
#include <math.h>

// Problem constants (fixed by the reference file)
#define B_    4
#define LQ_   4096
#define C_    384
#define NH_   6
#define NP_   4
#define HL_   64
#define WL_   64
#define LV_   (HL_ * WL_)          // 4096
#define ROWS_ (B_ * LQ_)           // 16384
#define EPS_  1e-6f
#define NOFF_ 48                   // NH*NL*NP*2
#define NLOG_ 24                   // NH*NL*NP

typedef unsigned short u16;
typedef unsigned int   u32;
typedef __bf16 bf16x8 __attribute__((ext_vector_type(8)));
typedef float  f32x4  __attribute__((ext_vector_type(4)));

__device__ __forceinline__ u16 f2bf(float f) {
    u32 u = __float_as_uint(f);
    u += 0x7fff + ((u >> 16) & 1);          // RTNE
    return (u16)(u >> 16);
}
__device__ __forceinline__ u32 pack2bf(float a, float b) {
    return (u32)f2bf(a) | ((u32)f2bf(b) << 16);
}

__device__ __forceinline__ f32x4 mfma16(bf16x8 a, bf16x8 b, f32x4 c) {
    return __builtin_amdgcn_mfma_f32_16x16x32_bf16(a, b, c, 0, 0, 0);
}

// async global->LDS, 16 bytes per lane; LDS dst must be wave-uniform base + lane*16
__device__ __forceinline__ void gl_lds16(const u16* g, u16* l) {
    __builtin_amdgcn_global_load_lds(
        (const __attribute__((address_space(1))) unsigned int*)g,
        (__attribute__((address_space(3))) unsigned int*)l, 16, 0, 0);
}

// ---------------------------------------------------------------------------
// Fused LayerNorm (blocks 0..8191, vectorized) + weight prep (rest).
// ---------------------------------------------------------------------------
#define LN_BLOCKS_   8192
#define PREP_BLOCKS_ 1273

__global__ __launch_bounds__(256) void ln_prep(
    const float* __restrict__ query, const float* __restrict__ feat,
    const float* __restrict__ qg, const float* __restrict__ qbv,
    const float* __restrict__ fg, const float* __restrict__ fbv,
    u16* __restrict__ qout, u16* __restrict__ fout,
    const float* __restrict__ Wv, const float* __restrict__ Wout,
    const float* __restrict__ Wo, const float* __restrict__ Wa,
    const float* __restrict__ bo, const float* __restrict__ ba,
    u16* __restrict__ WvT, u16* __restrict__ WoutT, u16* __restrict__ WcT,
    float* __restrict__ bias_c)
{
    if (blockIdx.x < LN_BLOCKS_) {
        int wid  = threadIdx.x >> 6;
        int lane = threadIdx.x & 63;
        int row  = blockIdx.x * 4 + wid;          // 0 .. 32767
        const float *src, *g, *bsh;
        u16* dst;
        int r;
        if (row < ROWS_) { src = query; g = qg; bsh = qbv; dst = qout; r = row; }
        else             { src = feat;  g = fg; bsh = fbv; dst = fout; r = row - ROWS_; }

        const float* x = src + (size_t)r * C_;
        float4 a4 = *(const float4*)(x + 4 * lane);
        float2 a2 = *(const float2*)(x + 256 + 2 * lane);
        float v0 = a4.x, v1 = a4.y, v2 = a4.z, v3 = a4.w, v4 = a2.x, v5 = a2.y;

        float s = v0 + v1 + v2 + v3 + v4 + v5;
#pragma unroll
        for (int off = 32; off; off >>= 1) s += __shfl_xor(s, off);
        float mu = s * (1.f / C_);

        float d0 = v0 - mu, d1 = v1 - mu, d2 = v2 - mu;
        float d3 = v3 - mu, d4 = v4 - mu, d5 = v5 - mu;
        float s2 = d0*d0 + d1*d1 + d2*d2 + d3*d3 + d4*d4 + d5*d5;
#pragma unroll
        for (int off = 32; off; off >>= 1) s2 += __shfl_xor(s2, off);
        float rs = rsqrtf(s2 * (1.f / C_) + EPS_);

        float4 g4 = *(const float4*)(g + 4 * lane);
        float4 b4 = *(const float4*)(bsh + 4 * lane);
        float2 g2 = *(const float2*)(g + 256 + 2 * lane);
        float2 b2 = *(const float2*)(bsh + 256 + 2 * lane);

        float o0 = d0 * rs * g4.x + b4.x;
        float o1 = d1 * rs * g4.y + b4.y;
        float o2 = d2 * rs * g4.z + b4.z;
        float o3 = d3 * rs * g4.w + b4.w;
        float o4 = d4 * rs * g2.x + b2.x;
        float o5 = d5 * rs * g2.y + b2.y;

        u16* y = dst + (size_t)r * C_;
        uint2 w0; w0.x = pack2bf(o0, o1); w0.y = pack2bf(o2, o3);
        *(uint2*)(y + 4 * lane) = w0;
        *(u32*)(y + 256 + 2 * lane) = pack2bf(o4, o5);
    } else {
        const int KN = 384 * 384;
        int idx = (blockIdx.x - LN_BLOCKS_) * 256 + threadIdx.x;
        if (idx < KN) {
            int n = idx / 384, k = idx - n * 384;
            WvT[idx] = f2bf(Wv[k * 384 + n]);
        } else if (idx < 2 * KN) {
            int t = idx - KN;
            int n = t / 384, k = t - n * 384;
            WoutT[t] = f2bf(Wout[k * 384 + n]);
        } else if (idx < 2 * KN + 80 * 384) {
            int t = idx - 2 * KN;
            int n = t / 384, k = t - n * 384;
            float v = (n < 48) ? Wo[k * 48 + n] : (n < 72 ? Wa[k * 24 + (n - 48)] : 0.f);
            WcT[t] = f2bf(v);
        } else if (idx < 2 * KN + 80 * 384 + 80) {
            int n = idx - (2 * KN + 80 * 384);
            bias_c[n] = (n < 48) ? bo[n] : (n < 72 ? ba[n - 48] : 0.f);
        }
    }
}

// ---------------------------------------------------------------------------
// Combined MFMA GEMM dispatch, 512 blocks x 256 threads, BK=32:
//   blocks 0..383:  value path, 128x128 tile: valb = fb @ WvT^T + bv (bf16)
//     XCD-affinity swizzle: m = g&127, n = g>>7 — the 3 N-blocks of one
//     M-strip (g, g+128, g+256) land on the SAME XCD (128%8==0), so A-strip
//     re-reads hit that XCD's L2 instead of L3/HBM.
//   blocks 384..511: small path, 128x80 tile: [offs|logits] = qb @ WcT^T + bias_c
// LDS: As 128x32 + Bs 128x32 = 16 KB.
// ---------------------------------------------------------------------------
__global__ __launch_bounds__(256) void gemm_combined(
    const u16* __restrict__ fb, const u16* __restrict__ qb,
    const u16* __restrict__ WvT, const u16* __restrict__ WcT,
    const float* __restrict__ bv, const float* __restrict__ bias_c,
    u16* __restrict__ valb, float* __restrict__ offs, float* __restrict__ logits)
{
    const int K = 384;
    __shared__ __align__(16) u16 As[128 * 32];
    __shared__ __align__(16) u16 Bs[128 * 32];

    int g    = blockIdx.x;
    int tid  = threadIdx.x;
    int lane = tid & 63, wid = tid >> 6;
    int fr = lane & 15, quad = lane >> 4;

    int srow = tid >> 2;                  // 0..63
    int scol = (tid & 3) * 8;             // element col within BK

    if (g < 384) {
        // ---------------- value path: 128x128 ----------------
        int m0 = (g & 127) * 128, n0 = (g >> 7) * 128;   // XCD-affinity swizzle
        const u16* agp0 = fb  + (size_t)(m0 + srow) * K + scol;
        const u16* agp1 = fb  + (size_t)(m0 + 64 + srow) * K + scol;
        const u16* bgp0 = WvT + (size_t)(n0 + srow) * K + scol;
        const u16* bgp1 = WvT + (size_t)(n0 + 64 + srow) * K + scol;
        u16* al0 = As + tid * 8;  u16* al1 = As + 2048 + tid * 8;
        u16* bl0 = Bs + tid * 8;  u16* bl1 = Bs + 2048 + tid * 8;

        int wm = (wid >> 1) * 64, wn = (wid & 1) * 64;

        f32x4 zero = {0.f, 0.f, 0.f, 0.f};
        f32x4 acc[4][4];
#pragma unroll
        for (int i = 0; i < 4; ++i)
#pragma unroll
            for (int j = 0; j < 4; ++j) acc[i][j] = zero;

        for (int k0 = 0; k0 < K; k0 += 32) {
            gl_lds16(agp0 + k0, al0);
            gl_lds16(agp1 + k0, al1);
            gl_lds16(bgp0 + k0, bl0);
            gl_lds16(bgp1 + k0, bl1);
            __syncthreads();
            bf16x8 af[4], bfr[4];
#pragma unroll
            for (int i = 0; i < 4; ++i)
                af[i] = *(bf16x8*)&As[(wm + i * 16 + fr) * 32 + quad * 8];
#pragma unroll
            for (int j = 0; j < 4; ++j)
                bfr[j] = *(bf16x8*)&Bs[(wn + j * 16 + fr) * 32 + quad * 8];
#pragma unroll
            for (int i = 0; i < 4; ++i)
#pragma unroll
                for (int j = 0; j < 4; ++j)
                    acc[i][j] = mfma16(af[i], bfr[j], acc[i][j]);
            __syncthreads();
        }

#pragma unroll
        for (int i = 0; i < 4; ++i) {
            int row = m0 + wm + i * 16 + quad * 4;
#pragma unroll
            for (int j = 0; j < 4; ++j) {
                int col = n0 + wn + j * 16 + fr;
                float bcol = bv[col];
#pragma unroll
                for (int r = 0; r < 4; ++r)
                    valb[(size_t)(row + r) * C_ + col] = f2bf(acc[i][j][r] + bcol);
            }
        }
    } else {
        // ---------------- small path: 128x80 ----------------
        int m0 = (g - 384) * 128;
        const u16* agp0 = qb + (size_t)(m0 + srow) * K + scol;
        const u16* agp1 = qb + (size_t)(m0 + 64 + srow) * K + scol;
        u16* al0 = As + tid * 8;  u16* al1 = As + 2048 + tid * 8;
        const u16* bgp0 = WcT + (size_t)srow * K + scol;           // rows 0..63
        const u16* bgp1 = WcT + (size_t)(64 + srow) * K + scol;    // rows 64..79 (tid<64)
        u16* bl0 = Bs + tid * 8;
        u16* bl1 = Bs + 2048 + tid * 8;

        int wm = wid * 32;

        f32x4 zero = {0.f, 0.f, 0.f, 0.f};
        f32x4 acc[2][5];
#pragma unroll
        for (int i = 0; i < 2; ++i)
#pragma unroll
            for (int j = 0; j < 5; ++j) acc[i][j] = zero;

        for (int k0 = 0; k0 < K; k0 += 32) {
            gl_lds16(agp0 + k0, al0);
            gl_lds16(agp1 + k0, al1);
            gl_lds16(bgp0 + k0, bl0);
            if (tid < 64) gl_lds16(bgp1 + k0, bl1);
            __syncthreads();
            bf16x8 af[2], bfr[5];
#pragma unroll
            for (int i = 0; i < 2; ++i)
                af[i] = *(bf16x8*)&As[(wm + i * 16 + fr) * 32 + quad * 8];
#pragma unroll
            for (int j = 0; j < 5; ++j)
                bfr[j] = *(bf16x8*)&Bs[(j * 16 + fr) * 32 + quad * 8];
#pragma unroll
            for (int i = 0; i < 2; ++i)
#pragma unroll
                for (int j = 0; j < 5; ++j)
                    acc[i][j] = mfma16(af[i], bfr[j], acc[i][j]);
            __syncthreads();
        }

#pragma unroll
        for (int i = 0; i < 2; ++i) {
            int row = m0 + wm + i * 16 + quad * 4;
#pragma unroll
            for (int j = 0; j < 5; ++j) {
                int col = j * 16 + fr;
                if (col < 72) {
                    float bcol = bias_c[col];
#pragma unroll
                    for (int r = 0; r < 4; ++r) {
                        float v = acc[i][j][r] + bcol;
                        if (col < 48) offs[(size_t)(row + r) * NOFF_ + col] = v;
                        else          logits[(size_t)(row + r) * NLOG_ + (col - 48)] = v;
                    }
                }
            }
        }
    }
}

// ---------------------------------------------------------------------------
// Standalone sampler: NO LDS, NO barriers. One thread = one (q, d-chunk):
// softmax+coords in registers, 16 bf16x8 gathers, one 16B coalesced store.
// 384 threads = 8 queries/block; 2048 blocks; XCD swizzle keeps one batch's
// value (3.1 MB) per XCD-pair L2.
// ---------------------------------------------------------------------------
__global__ __launch_bounds__(384) void sampler(
    const u16*  __restrict__ value,    // [B*LV, 384] bf16
    const float* __restrict__ rp,      // [B*LQ, 2]
    const float* __restrict__ offs,    // [B*LQ, 48]
    const float* __restrict__ logits,  // [B*LQ, 24]
    u16* __restrict__ attn)            // [B*LQ, 384] bf16
{
    int t = threadIdx.x;
    int g = blockIdx.x;
    int b     = (g & 7) >> 1;                        // batch -> XCD pair
    int local = ((g >> 3) << 1) | (g & 1);           // 0..511 within batch
    int q  = t / 48, dc = t - q * 48;
    int h  = dc >> 3;
    int col0 = dc << 3;                              // 0,8,...,376
    int r  = b * LQ_ + local * 8 + q;

    float4 lg  = *(const float4*)(logits + (size_t)r * NLOG_ + h * 4);
    float2 rpv = *(const float2*)(rp + (size_t)r * 2);
    float4 of0 = *(const float4*)(offs + (size_t)r * NOFF_ + h * 8);
    float4 of1 = *(const float4*)(offs + (size_t)r * NOFF_ + h * 8 + 4);

    float mx = fmaxf(fmaxf(lg.x, lg.y), fmaxf(lg.z, lg.w));
    float e0 = __expf(lg.x - mx), e1 = __expf(lg.y - mx);
    float e2 = __expf(lg.z - mx), e3 = __expf(lg.w - mx);
    float rden = 1.f / (e0 + e1 + e2 + e3);
    float aws[4] = {e0 * rden, e1 * rden, e2 * rden, e3 * rden};
    float oxs[4] = {of0.x, of0.z, of1.x, of1.z};
    float oys[4] = {of0.y, of0.w, of1.y, of1.w};

    const u16* vbase = value + (size_t)b * LV_ * C_ + col0;
    float acc[8] = {0.f, 0.f, 0.f, 0.f, 0.f, 0.f, 0.f, 0.f};
#pragma unroll
    for (int p = 0; p < NP_; ++p) {
        float x = rpv.x * (float)WL_ + oxs[p] - 0.5f;
        float y = rpv.y * (float)HL_ + oys[p] - 0.5f;
        float x0f = floorf(x), y0f = floorf(y);
        float wx = x - x0f, wy = y - y0f;
        int x0 = (int)x0f, y0 = (int)y0f;
#pragma unroll
        for (int c = 0; c < 4; ++c) {
            int xi = x0 + (c & 1);
            int yi = y0 + (c >> 1);
            bool valid = (xi >= 0) && (xi < WL_) && (yi >= 0) && (yi < HL_);
            int xc = xi < 0 ? 0 : (xi > WL_ - 1 ? WL_ - 1 : xi);
            int yc = yi < 0 ? 0 : (yi > HL_ - 1 ? HL_ - 1 : yi);
            float w = ((c & 1) ? wx : 1.f - wx) * ((c >> 1) ? wy : 1.f - wy) * aws[p];
            w = valid ? w : 0.f;
            bf16x8 vv = *(const bf16x8*)(vbase + (size_t)(yc * WL_ + xc) * C_);
#pragma unroll
            for (int e = 0; e < 8; ++e) acc[e] += w * (float)vv[e];
        }
    }

    uint4 o;
    o.x = pack2bf(acc[0], acc[1]);
    o.y = pack2bf(acc[2], acc[3]);
    o.z = pack2bf(acc[4], acc[5]);
    o.w = pack2bf(acc[6], acc[7]);
    *(uint4*)(attn + (size_t)r * C_ + col0) = o;
}

// ---------------------------------------------------------------------------
// Out GEMM: out = query + gamma * (attn @ WoutT^T + bout). 128x128 tile,
// BK=32, XCD-affinity swizzle (same-m blocks share an XCD for attn L2 reuse).
// 384 blocks x 256 threads.
// ---------------------------------------------------------------------------
__global__ __launch_bounds__(256) void out_gemm(
    const u16* __restrict__ A, const u16* __restrict__ Bt,
    const float* __restrict__ bout, const float* __restrict__ gamma,
    const float* __restrict__ query, float* __restrict__ out)
{
    const int K = 384;
    __shared__ __align__(16) u16 As[128 * 32];
    __shared__ __align__(16) u16 Bs[128 * 32];

    int g    = blockIdx.x;
    int tid  = threadIdx.x;
    int lane = tid & 63, wid = tid >> 6;
    int fr = lane & 15, quad = lane >> 4;

    int srow = tid >> 2;
    int scol = (tid & 3) * 8;

    int m0 = (g & 127) * 128, n0 = (g >> 7) * 128;   // XCD-affinity swizzle
    const u16* agp0 = A  + (size_t)(m0 + srow) * K + scol;
    const u16* agp1 = A  + (size_t)(m0 + 64 + srow) * K + scol;
    const u16* bgp0 = Bt + (size_t)(n0 + srow) * K + scol;
    const u16* bgp1 = Bt + (size_t)(n0 + 64 + srow) * K + scol;
    u16* al0 = As + tid * 8;  u16* al1 = As + 2048 + tid * 8;
    u16* bl0 = Bs + tid * 8;  u16* bl1 = Bs + 2048 + tid * 8;

    int wm = (wid >> 1) * 64, wn = (wid & 1) * 64;

    f32x4 zero = {0.f, 0.f, 0.f, 0.f};
    f32x4 acc[4][4];
#pragma unroll
    for (int i = 0; i < 4; ++i)
#pragma unroll
        for (int j = 0; j < 4; ++j) acc[i][j] = zero;

    for (int k0 = 0; k0 < K; k0 += 32) {
        gl_lds16(agp0 + k0, al0);
        gl_lds16(agp1 + k0, al1);
        gl_lds16(bgp0 + k0, bl0);
        gl_lds16(bgp1 + k0, bl1);
        __syncthreads();
        bf16x8 af[4], bfr[4];
#pragma unroll
        for (int i = 0; i < 4; ++i)
            af[i] = *(bf16x8*)&As[(wm + i * 16 + fr) * 32 + quad * 8];
#pragma unroll
        for (int j = 0; j < 4; ++j)
            bfr[j] = *(bf16x8*)&Bs[(wn + j * 16 + fr) * 32 + quad * 8];
#pragma unroll
        for (int i = 0; i < 4; ++i)
#pragma unroll
            for (int j = 0; j < 4; ++j)
                acc[i][j] = mfma16(af[i], bfr[j], acc[i][j]);
        __syncthreads();
    }

#pragma unroll
    for (int i = 0; i < 4; ++i) {
        int row = m0 + wm + i * 16 + quad * 4;
#pragma unroll
        for (int j = 0; j < 4; ++j) {
            int col = n0 + wn + j * 16 + fr;
            float bc = bout[col], gm = gamma[col];
#pragma unroll
            for (int r = 0; r < 4; ++r) {
                size_t o = (size_t)(row + r) * C_ + col;
                out[o] = query[o] + gm * (acc[i][j][r] + bc);
            }
        }
    }
}

// ---------------------------------------------------------------------------
extern "C" void kernel_launch(void* const* d_in, const int* in_sizes, int n_in,
                              void* d_out, int out_size, void* d_ws, size_t ws_size,
                              hipStream_t stream)
{
    const float* query  = (const float*)d_in[0];
    const float* rp     = (const float*)d_in[1];
    const float* feat   = (const float*)d_in[2];
    const float* gamma  = (const float*)d_in[9];
    const float* Wv     = (const float*)d_in[10];
    const float* bv     = (const float*)d_in[11];
    const float* Wo     = (const float*)d_in[12];
    const float* bo     = (const float*)d_in[13];
    const float* Wa     = (const float*)d_in[14];
    const float* ba     = (const float*)d_in[15];
    const float* Wout   = (const float*)d_in[16];
    const float* bout   = (const float*)d_in[17];
    float* out = (float*)d_out;

    // Workspace layout
    u16* wsu    = (u16*)d_ws;
    u16* qb     = wsu;                                   // 16384*384
    u16* fb     = qb    + (size_t)ROWS_ * C_;
    u16* valb   = fb    + (size_t)ROWS_ * C_;
    u16* attnb  = valb  + (size_t)ROWS_ * C_;
    u16* WvT    = attnb + (size_t)ROWS_ * C_;            // 384*384
    u16* WoutT  = WvT   + 384 * 384;
    u16* WcT    = WoutT + 384 * 384;                     // 80*384
    float* offs   = (float*)(WcT + 80 * 384);            // 16384*48
    float* logits = offs + (size_t)ROWS_ * NOFF_;        // 16384*24
    float* bias_c = logits + (size_t)ROWS_ * NLOG_;      // 80

    // 1) LayerNorm (q,f -> bf16, vectorized) + weight transpose/convert
    ln_prep<<<LN_BLOCKS_ + PREP_BLOCKS_, 256, 0, stream>>>(
        query, feat,
        (const float*)d_in[5], (const float*)d_in[6],
        (const float*)d_in[7], (const float*)d_in[8],
        qb, fb, Wv, Wout, Wo, Wa, bo, ba, WvT, WoutT, WcT, bias_c);

    // 2) value GEMM 128x128 (384 blocks, XCD-affinity) + offs/logits GEMM
    gemm_combined<<<512, 256, 0, stream>>>(fb, qb, WvT, WcT, bv, bias_c,
                                           valb, offs, logits);

    // 3) sampler: barrier-free, register-only, coalesced bf16 attn out
    sampler<<<2048, 384, 0, stream>>>(valb, rp, offs, logits, attnb);

    // 4) out = query + gamma * (attn @ Wout + bout), BK=32, XCD-affinity
    out_gemm<<<384, 256, 0, stream>>>(attnb, WoutT, bout, gamma, query, out);
}